// Round 7
// baseline (261.072 us; speedup 1.0000x reference)
//
#include <hip/hip_runtime.h>

#define DEVFN __device__ __forceinline__

typedef __attribute__((ext_vector_type(8))) short short8;
typedef __attribute__((ext_vector_type(4))) float floatx4;
typedef unsigned short u16;
typedef unsigned int u32;

constexpr int B_   = 2;
constexpr int CIN  = 16;
constexpr int COUT = 16;
constexpr int T_   = 31;
constexpr int H_   = 128;
constexpr int W_   = 128;
constexpr int OC   = 6 * COUT;   // 96
constexpr int HW   = H_ * W_;    // 16384
constexpr int KVOL = CIN * 27;   // 432
constexpr int KP   = 448;        // K padded to 14 * 32

// padded x layout [b][TP][HP][WP][16ci], fp16
constexpr int TP = T_ + 2;       // 33
constexpr int HP = H_ + 2;       // 130
constexpr int WP = W_ + 2;       // 130
constexpr int Sh = WP * 16;      // elems per hh step
constexpr int St = HP * Sh;      // elems per tt step
constexpr int NPAD  = B_ * TP * HP * WP;   // 1,115,400 positions
// +1 zeroed t-slab: fused kernel's pad column t=31 reads padded tt up to 33.
constexpr int NPADX = NPAD + HP * WP;      // 1,132,300
constexpr int PADBLK = (NPADX + 255) / 256;
constexpr int WBLK   = (OC * KP + 255) / 256;

// A-in-LDS: one phase = 7 k-steps, layout [sl(7)][m(6)][quad(4)][n(16)][j(8)]
constexpr int APH = 7 * 6 * 4 * 16 * 8;  // 21504 elems = 43008 B per phase

// gates-in-LDS (aliased over A buffer after conv): [g(6)][c(16)][t*8+w],
// c-stride padded 264 -> 268 elems so the 4 quads land on distinct banks.
constexpr int GSTR = 268;
constexpr int GS   = 16 * GSTR;   // 4288
constexpr int GLDS = 6 * GS;      // 25728 elems = 51456 B

DEVFN float sigmoid_(float v) { return 1.f / (1.f + __expf(-v)); }
DEVFN float tanh_(float v)    { return 1.f - 2.f / (__expf(2.f * v) + 1.f); }

DEVFN u16 f2h(float v) {  // RNE f32 -> fp16 raw bits
  _Float16 h = (_Float16)v;
  u16 u; __builtin_memcpy(&u, &h, 2); return u;
}
DEVFN float h2f(u16 u) {
  _Float16 h; __builtin_memcpy(&h, &u, 2); return (float)h;
}

// delta (in elems) into padded-x for kernel offset off = kd*9+kh*3+kw;
// off==27 (the K pad) clamps to 26 — A weights there are zero.
DEVFN constexpr int dOff(int off) {
  const int o = (off < 27) ? off : 26;
  return (o / 9) * St + ((o % 9) / 3) * Sh + (o % 3) * 16;
}

// ---------------------------------------------------------------------------
// Prep (merged): blocks [0, PADBLK) do x fp32->fp16 pad/transpose, ONE
// position per thread — lane stride in x is 4 B (fully coalesced; the R5
// 2-pos variant had 8 B stride = 50% line utilization and regressed the
// "rest" by ~30-45 us). Blocks [PADBLK, PADBLK+WBLK) reorder weights.
// ---------------------------------------------------------------------------
__global__ __launch_bounds__(256) void prep_kernel(const float* __restrict__ x,
                                                   const float* __restrict__ cw,
                                                   u16* __restrict__ xh,
                                                   u16* __restrict__ wr) {
  if (blockIdx.x < PADBLK) {
    const int idx = blockIdx.x * 256 + threadIdx.x;
    if (idx >= NPADX) return;
    int r = idx;
    const int ww = r % WP; r /= WP;
    const int hh = r % HP; r /= HP;
    const int tt = r % TP; const int b = r / TP;
    const bool in_ = (b < B_) & (tt >= 1) & (tt <= T_) & (hh >= 1) &
                     (hh <= H_) & (ww >= 1) & (ww <= W_);
    const int ts = in_ ? tt - 1 : 0, hs = in_ ? hh - 1 : 0,
              ws = in_ ? ww - 1 : 0;
    const int bs = (b < B_) ? b : 0;
    const float* xp = x + ((size_t)bs * CIN * T_ + ts) * HW + hs * W_ + ws;
    u32 ph[8];
#pragma unroll
    for (int ci = 0; ci < 16; ++ci) {
      const float v = in_ ? xp[ci * (T_ * HW)] : 0.f;
      const u16 hu = f2h(v);
      if (ci & 1) ph[ci >> 1] |= ((u32)hu) << 16;
      else        ph[ci >> 1] = hu;
    }
    uint4* dh = (uint4*)(xh + (size_t)idx * 16);
    dh[0] = make_uint4(ph[0], ph[1], ph[2], ph[3]);
    dh[1] = make_uint4(ph[4], ph[5], ph[6], ph[7]);
  } else {
    // weights [oc][ci][27] fp32 -> [s(14)][m(6)][quad(4)][n(16)][j(8)] fp16,
    // oc = m*16+n, k = s*32+quad*8+j.
    const int idx = (blockIdx.x - PADBLK) * 256 + threadIdx.x;
    if (idx >= OC * KP) return;
    const int j    = idx & 7;
    const int n    = (idx >> 3) & 15;
    const int quad = (idx >> 7) & 3;
    const int m    = (idx >> 9) % 6;
    const int s    = idx / 3072;
    const int oc   = m * 16 + n;
    const int kk   = s * 32 + quad * 8 + j;
    const int off  = kk >> 4, ci = kk & 15;
    const float v  = (off < 27) ? cw[oc * KVOL + ci * 27 + off] : 0.f;
    wr[idx] = f2h(v);
  }
}

// ---------------------------------------------------------------------------
// One k-phase (7 steps), PH compile-time so dOff folds to immediates.
// 2 B-loads + 12 MFMA per step (8-wave variant). Compiler-scheduled (R4's
// hand pipeline regressed 155->190 us — do not re-introduce explicit
// prefetch buffers here).
// ---------------------------------------------------------------------------
template <int PH>
DEVFN void kphase(const u16* __restrict__ xp0, const u16* __restrict__ xp1,
                  const u16* As, int n, int quad, int qhalf,
                  floatx4 (&acc)[6][2]) {
#pragma unroll
  for (int sl = 0; sl < 7; ++sl) {
    const int s = PH * 7 + sl;
    const int d = qhalf ? dOff(2 * s + 1) : dOff(2 * s);
    short8 bh[2];
    bh[0] = *(const short8*)(xp0 + d);
    bh[1] = *(const short8*)(xp1 + d);
#pragma unroll
    for (int m = 0; m < 6; ++m) {
      const short8 a =
          *(const short8*)(As + (sl * 6 + m) * 512 + quad * 128 + n * 8);
#pragma unroll
      for (int j = 0; j < 2; ++j)
        acc[m][j] =
            __builtin_amdgcn_mfma_f32_16x16x32_f16(a, bh[j], acc[m][j], 0, 0, 0);
    }
  }
}

// ---------------------------------------------------------------------------
// Fused conv + bidirectional SRU scan — 8-wave occupancy variant (R6,
// measured best: 146.4 us, VGPR 64, occ 34%).
// Block = 8 waves (512 thr) = one (b, h, 8w) tile covering ALL t:
//   wave wv owns t = wv*4 + j*2 + th (j=0..1, th=(lane>>3)&1) -> acc[6][2].
//   t==31 is a discarded pad col. MFMA fragment layouts HW-verified:
//   A rows m=lane&15 (=oc), B cols n=lane&15 (=pos), D col=lane&15 (=pos),
//   row=quad*4+reg (=oc).
// B-taps from GLOBAL (L2-served); A staged to LDS via reg round-trip in 2
// phases; serial scan (R1 form, measured best): threads 0..127 run full
// fwd+bwd per (c,w) series, htl in regs, no barrier crossing.
// ---------------------------------------------------------------------------
__global__ __launch_bounds__(512, 4) void conv_sru_fused(
    const u16* __restrict__ xh, const u16* __restrict__ wr,
    const float* __restrict__ cb, float* __restrict__ out) {
  const int lane = threadIdx.x & 63, wv = threadIdx.x >> 6;  // wv = 0..7
  const int n = lane & 15, quad = lane >> 4;
  const int qhalf = quad >> 1, cihalf = quad & 1;
  const int th = n >> 3, wloc = n & 7;
  const int wbase = blockIdx.x * 8;
  const int h = blockIdx.y;
  const int b = blockIdx.z;

  __shared__ __align__(16) u16 As[GLDS];  // 51456 B (A phases alias gates)

  // per-thread base pointers for the 2 column tiles (j -> t += 2)
  const u16 *xp0, *xp1;
  {
    const int t0 = wv * 4 + th;
    const size_t pb =
        ((size_t)((b * TP + t0) * HP + h) * WP + wbase + wloc) * 16 +
        cihalf * 8;
    xp0 = xh + pb;
    xp1 = xh + pb + (size_t)2 * St;
  }

  floatx4 acc[6][2];
#pragma unroll
  for (int m = 0; m < 6; ++m)
#pragma unroll
    for (int j = 0; j < 2; ++j) acc[m][j] = (floatx4)(0.f);

  // phase 0: stage A[s=0..6], compute
  for (int i = threadIdx.x; i < APH / 8; i += 512)
    ((uint4*)As)[i] = ((const uint4*)wr)[i];
  __syncthreads();
  kphase<0>(xp0, xp1, As, n, quad, qhalf, acc);

  // phase 1: restage A[s=7..13], compute
  __syncthreads();
  for (int i = threadIdx.x; i < APH / 8; i += 512)
    ((uint4*)As)[i] = ((const uint4*)(wr + APH))[i];
  __syncthreads();
  kphase<1>(xp0, xp1, As, n, quad, qhalf, acc);

  // epilogue: bias + activation -> gates in LDS (overwrites A staging)
  __syncthreads();
#pragma unroll
  for (int m = 0; m < 6; ++m) {
    const bool isTanh = (m == 0) || (m == 5);
#pragma unroll
    for (int rr = 0; rr < 4; ++rr) {
      const int c = quad * 4 + rr;
      const float bias = cb[m * 16 + c];
#pragma unroll
      for (int j = 0; j < 2; ++j) {
        const int t = wv * 4 + j * 2 + th;
        float v = acc[m][j][rr] + bias;
        v = isTanh ? tanh_(v) : sigmoid_(v);
        As[(m * 16 + c) * GSTR + t * 8 + wloc] = f2h(v);
      }
    }
  }
  __syncthreads();

  // bidirectional scan: 128 threads, one (c, w) series each (T_=31 steps).
  if (threadIdx.x < 128) {
    const int c = threadIdx.x >> 3;
    const int w = threadIdx.x & 7;
    const int gb = c * GSTR + w;
    float htl[T_];
    float C = 0.f;
#pragma unroll
    for (int t = 0; t < T_; ++t) {
      const float wx = h2f(As[0 * GS + gb + t * 8]);
      const float f  = h2f(As[1 * GS + gb + t * 8]);
      const float r  = h2f(As[3 * GS + gb + t * 8]);
      const float xv = h2f(As[5 * GS + gb + t * 8]);
      C = (t == 0) ? (1.f - f) : (f * C + (1.f - f) * wx);
      htl[t] = r * C + (1.f - r) * xv;
    }
    const size_t ob =
        ((size_t)(b * COUT + c) * T_) * HW + h * W_ + wbase + w;
    float C2 = 0.f;
#pragma unroll
    for (int t = T_ - 1; t >= 0; --t) {
      const float wx = h2f(As[0 * GS + gb + t * 8]);
      const float f2 = h2f(As[2 * GS + gb + t * 8]);
      const float r2 = h2f(As[4 * GS + gb + t * 8]);
      const float xv = h2f(As[5 * GS + gb + t * 8]);
      C2 = (t == T_ - 1) ? (1.f - f2) : (f2 * C2 + (1.f - f2) * wx);
      const float htr = r2 * C2 + (1.f - r2) * xv;
      out[ob + (size_t)t * HW] = htl[t] + htr;
    }
  }
}

// ---------------------------------------------------------------------------
// Fallback path (only if ws too small for the fused MFMA path).
// ---------------------------------------------------------------------------
__global__ __launch_bounds__(256) void sru_scan_kernel(
    const u16* __restrict__ g, float* __restrict__ out) {
  const int idx  = blockIdx.x * 256 + threadIdx.x;
  const int sp   = idx & (HW - 1);
  const int bc   = idx >> 14;
  const int base = bc * (T_ * HW) + sp;
  const int P    = B_ * COUT * T_ * HW;

  const u16* gWx = g + 0 * P + base;
  const u16* gF  = g + 1 * P + base;
  const u16* gF2 = g + 2 * P + base;
  const u16* gR  = g + 3 * P + base;
  const u16* gR2 = g + 4 * P + base;
  const u16* gX  = g + 5 * P + base;

  float wxs[T_], xs[T_], htl[T_];
  float C = 0.f;
#pragma unroll
  for (int t = 0; t < T_; ++t) {
    const float wx = h2f(gWx[t * HW]);
    const float f  = h2f(gF[t * HW]);
    const float r  = h2f(gR[t * HW]);
    const float xv = h2f(gX[t * HW]);
    wxs[t] = wx;
    xs[t]  = xv;
    C = (t == 0) ? (1.f - f) : (f * C + (1.f - f) * wx);
    htl[t] = r * C + (1.f - r) * xv;
  }
  float C2 = 0.f;
#pragma unroll
  for (int t = T_ - 1; t >= 0; --t) {
    const float f2 = h2f(gF2[t * HW]);
    const float r2 = h2f(gR2[t * HW]);
    C2 = (t == T_ - 1) ? (1.f - f2) : (f2 * C2 + (1.f - f2) * wxs[t]);
    const float htr = r2 * C2 + (1.f - r2) * xs[t];
    out[base + t * HW] = htl[t] + htr;
  }
}

__global__ __launch_bounds__(256) void conv_gates_kernel(
    const float* __restrict__ x, const float* __restrict__ cw,
    const float* __restrict__ cb, u16* __restrict__ gates) {
  const int sp = blockIdx.x * 256 + threadIdx.x;
  const int oc = blockIdx.y;
  const int bt = blockIdx.z;
  const int b  = bt / T_;
  const int t  = bt - b * T_;
  const int h  = sp >> 7;
  const int wc = sp & (W_ - 1);

  __shared__ float wsh[KVOL];
  for (int i = threadIdx.x; i < KVOL; i += 256) wsh[i] = cw[oc * KVOL + i];
  __syncthreads();

  float acc = cb[oc];
  const float* xb = x + b * (CIN * T_ * HW);
  for (int ci = 0; ci < CIN; ++ci) {
    const float* xc = xb + ci * (T_ * HW);
#pragma unroll
    for (int kd = 0; kd < 3; ++kd) {
      const int tt = t + kd - 1;
      if ((unsigned)tt >= (unsigned)T_) continue;
      const float* xt = xc + tt * HW;
#pragma unroll
      for (int kh = 0; kh < 3; ++kh) {
        const int hh = h + kh - 1;
        if ((unsigned)hh >= (unsigned)H_) continue;
        const float* xr = xt + hh * W_;
        const float* wrp = &wsh[(ci * 3 + kd) * 9 + kh * 3];
        if (wc > 0)      acc += wrp[0] * xr[wc - 1];
        acc += wrp[1] * xr[wc];
        if (wc < W_ - 1) acc += wrp[2] * xr[wc + 1];
      }
    }
  }
  const int g = oc >> 4, c = oc & 15;
  const float av = (g == 0 || g == 5) ? tanh_(acc) : sigmoid_(acc);
  const int off = (((g * B_ + b) * COUT + c) * T_ + t) * HW + sp;
  gates[off] = f2h(av);
}

extern "C" void kernel_launch(void* const* d_in, const int* in_sizes, int n_in,
                              void* d_out, int out_size, void* d_ws,
                              size_t ws_size, hipStream_t stream) {
  (void)in_sizes; (void)n_in; (void)out_size;
  const float* x  = (const float*)d_in[0];
  const float* cw = (const float*)d_in[1];
  const float* cb = (const float*)d_in[2];
  float* out = (float*)d_out;

  const size_t planeElems = (size_t)B_ * COUT * T_ * HW;    // 16,252,928
  const size_t szGatesH = 6 * planeElems * sizeof(u16);     // 195,035,136
  const size_t szX      = (size_t)NPADX * 16 * sizeof(u16); // 36,233,600
  const size_t szW      = (size_t)OC * KP * sizeof(u16);    // 86,016

  char* p = (char*)d_ws;
  if (ws_size >= szX + szW) {
    u16* xh  = (u16*)p;
    u16* wrp = (u16*)(p + szX);
    prep_kernel<<<PADBLK + WBLK, 256, 0, stream>>>(x, cw, xh, wrp);
    const dim3 gfused(W_ / 8, H_, B_);   // 16 x 128 x 2 = 4096 blocks
    conv_sru_fused<<<gfused, 512, 0, stream>>>(xh, wrp, cb, out);
  } else if (ws_size >= szGatesH) {
    u16* gates = (u16*)p;
    const dim3 gdir(HW / 256, OC, B_ * T_);
    conv_gates_kernel<<<gdir, 256, 0, stream>>>(x, cw, cb, gates);
    const int scanBlocks = (B_ * COUT * HW) / 256;
    sru_scan_kernel<<<scanBlocks, 256, 0, stream>>>(gates, out);
  }
}

// Round 8
// 256.117 us; speedup vs baseline: 1.0193x; 1.0193x over previous
//
#include <hip/hip_runtime.h>

#define DEVFN __device__ __forceinline__

typedef __attribute__((ext_vector_type(8))) short short8;
typedef __attribute__((ext_vector_type(4))) float floatx4;
typedef unsigned short u16;
typedef unsigned int u32;

constexpr int B_   = 2;
constexpr int CIN  = 16;
constexpr int COUT = 16;
constexpr int T_   = 31;
constexpr int H_   = 128;
constexpr int W_   = 128;
constexpr int OC   = 6 * COUT;   // 96
constexpr int HW   = H_ * W_;    // 16384
constexpr int KVOL = CIN * 27;   // 432
constexpr int KP   = 448;        // K padded to 14 * 32

// padded x layout [b][TP][HP][WP][16ci], fp16
constexpr int TP = T_ + 2;       // 33
constexpr int HP = H_ + 2;       // 130
constexpr int WP = W_ + 2;       // 130
constexpr int Sh = WP * 16;      // elems per hh step
constexpr int St = HP * Sh;      // elems per tt step
constexpr int NPAD  = B_ * TP * HP * WP;   // 1,115,400 positions
// +1 zeroed t-slab: fused kernel's pad column t=31 reads padded tt up to 33.
constexpr int NPADX = NPAD + HP * WP;      // 1,132,300
constexpr int PADBLK = (NPADX + 255) / 256;
constexpr int WBLK   = (OC * KP + 255) / 256;

// A-in-LDS: one phase = 7 k-steps, layout [sl(7)][m(6)][quad(4)][n(16)][j(8)]
constexpr int APH = 7 * 6 * 4 * 16 * 8;  // 21504 elems = 43008 B per phase

// gates-in-LDS (alias over A buffer after conv): [ser(128)][t(32)][6 u16],
// series stride 198 u16 = 396 B = 99 words === 3 (mod 32) -> scan lanes
// spread 2/bank (free, m136). One (c,w,t)'s 6 gates are contiguous: the
// scan reads 3 x u32 per step (batched 8 steps ahead) instead of 4 scalar
// ds_read_u16 on the serial chain.
constexpr int SSTR = 198;                // u16 per series (32*6 pad 396B)
constexpr int GL2  = 128 * SSTR;         // 25344 u16 = 50688 B
constexpr int LSN  = (GL2 > APH) ? GL2 : APH;   // 25344 u16

DEVFN float sigmoid_(float v) { return 1.f / (1.f + __expf(-v)); }
DEVFN float tanh_(float v)    { return 1.f - 2.f / (__expf(2.f * v) + 1.f); }

DEVFN u16 f2h(float v) {  // RNE f32 -> fp16 raw bits
  _Float16 h = (_Float16)v;
  u16 u; __builtin_memcpy(&u, &h, 2); return u;
}
DEVFN float h2f(u16 u) {
  _Float16 h; __builtin_memcpy(&h, &u, 2); return (float)h;
}

// delta (in elems) into padded-x for kernel offset off = kd*9+kh*3+kw;
// off==27 (the K pad) clamps to 26 — A weights there are zero.
DEVFN constexpr int dOff(int off) {
  const int o = (off < 27) ? off : 26;
  return (o / 9) * St + ((o % 9) / 3) * Sh + (o % 3) * 16;
}

// ---------------------------------------------------------------------------
// Prep (merged): blocks [0, PADBLK) do x fp32->fp16 pad/transpose, ONE
// position per thread (4 B lane stride, fully coalesced); blocks
// [PADBLK, PADBLK+WBLK) reorder weights to the LDS-ready layout.
// ---------------------------------------------------------------------------
__global__ __launch_bounds__(256) void prep_kernel(const float* __restrict__ x,
                                                   const float* __restrict__ cw,
                                                   u16* __restrict__ xh,
                                                   u16* __restrict__ wr) {
  if (blockIdx.x < PADBLK) {
    const int idx = blockIdx.x * 256 + threadIdx.x;
    if (idx >= NPADX) return;
    int r = idx;
    const int ww = r % WP; r /= WP;
    const int hh = r % HP; r /= HP;
    const int tt = r % TP; const int b = r / TP;
    const bool in_ = (b < B_) & (tt >= 1) & (tt <= T_) & (hh >= 1) &
                     (hh <= H_) & (ww >= 1) & (ww <= W_);
    const int ts = in_ ? tt - 1 : 0, hs = in_ ? hh - 1 : 0,
              ws = in_ ? ww - 1 : 0;
    const int bs = (b < B_) ? b : 0;
    const float* xp = x + ((size_t)bs * CIN * T_ + ts) * HW + hs * W_ + ws;
    u32 ph[8];
#pragma unroll
    for (int ci = 0; ci < 16; ++ci) {
      const float v = in_ ? xp[ci * (T_ * HW)] : 0.f;
      const u16 hu = f2h(v);
      if (ci & 1) ph[ci >> 1] |= ((u32)hu) << 16;
      else        ph[ci >> 1] = hu;
    }
    uint4* dh = (uint4*)(xh + (size_t)idx * 16);
    dh[0] = make_uint4(ph[0], ph[1], ph[2], ph[3]);
    dh[1] = make_uint4(ph[4], ph[5], ph[6], ph[7]);
  } else {
    // weights [oc][ci][27] fp32 -> [s(14)][m(6)][quad(4)][n(16)][j(8)] fp16,
    // oc = m*16+n, k = s*32+quad*8+j.
    const int idx = (blockIdx.x - PADBLK) * 256 + threadIdx.x;
    if (idx >= OC * KP) return;
    const int j    = idx & 7;
    const int n    = (idx >> 3) & 15;
    const int quad = (idx >> 7) & 3;
    const int m    = (idx >> 9) % 6;
    const int s    = idx / 3072;
    const int oc   = m * 16 + n;
    const int kk   = s * 32 + quad * 8 + j;
    const int off  = kk >> 4, ci = kk & 15;
    const float v  = (off < 27) ? cw[oc * KVOL + ci * 27 + off] : 0.f;
    wr[idx] = f2h(v);
  }
}

// ---------------------------------------------------------------------------
// One k-phase (7 steps), PH compile-time so dOff folds to immediates.
// 2 B-loads + 12 MFMA per step (8-wave variant). Compiler-scheduled (R4's
// hand pipeline regressed 155->190 us — do not re-introduce explicit
// prefetch buffers here).
// ---------------------------------------------------------------------------
template <int PH>
DEVFN void kphase(const u16* __restrict__ xp0, const u16* __restrict__ xp1,
                  const u16* As, int n, int quad, int qhalf,
                  floatx4 (&acc)[6][2]) {
#pragma unroll
  for (int sl = 0; sl < 7; ++sl) {
    const int s = PH * 7 + sl;
    const int d = qhalf ? dOff(2 * s + 1) : dOff(2 * s);
    short8 bh[2];
    bh[0] = *(const short8*)(xp0 + d);
    bh[1] = *(const short8*)(xp1 + d);
#pragma unroll
    for (int m = 0; m < 6; ++m) {
      const short8 a =
          *(const short8*)(As + (sl * 6 + m) * 512 + quad * 128 + n * 8);
#pragma unroll
      for (int j = 0; j < 2; ++j)
        acc[m][j] =
            __builtin_amdgcn_mfma_f32_16x16x32_f16(a, bh[j], acc[m][j], 0, 0, 0);
    }
  }
}

// ---------------------------------------------------------------------------
// Fused conv + bidirectional SRU scan — 8-wave variant (R6 conv structure,
// measured best 146 us) + interleaved gate layout & batched scan loads.
// Block = 8 waves (512 thr) = one (b, h, 8w) tile covering ALL t:
//   wave wv owns t = wv*4 + j*2 + th (j=0..1, th=(lane>>3)&1) -> acc[6][2].
//   t==31 is a discarded pad col. MFMA fragment layouts HW-verified.
// Scan: threads 0..127, one (c,w) series each; gates for a step are 3
// contiguous u32 in LDS; loads batched 8 steps ahead of the dependent
// chain (static indexing -> registers), cutting the serial LDS latency
// from ~31x150 cyc to 4 chunk-waits per pass.
// ---------------------------------------------------------------------------
__global__ __launch_bounds__(512, 4) void conv_sru_fused(
    const u16* __restrict__ xh, const u16* __restrict__ wr,
    const float* __restrict__ cb, float* __restrict__ out) {
  const int lane = threadIdx.x & 63, wv = threadIdx.x >> 6;  // wv = 0..7
  const int n = lane & 15, quad = lane >> 4;
  const int qhalf = quad >> 1, cihalf = quad & 1;
  const int th = n >> 3, wloc = n & 7;
  const int wbase = blockIdx.x * 8;
  const int h = blockIdx.y;
  const int b = blockIdx.z;

  __shared__ __align__(16) u16 Ls[LSN];  // 50688 B (A phases alias gates)

  // per-thread base pointers for the 2 column tiles (j -> t += 2)
  const u16 *xp0, *xp1;
  {
    const int t0 = wv * 4 + th;
    const size_t pb =
        ((size_t)((b * TP + t0) * HP + h) * WP + wbase + wloc) * 16 +
        cihalf * 8;
    xp0 = xh + pb;
    xp1 = xh + pb + (size_t)2 * St;
  }

  floatx4 acc[6][2];
#pragma unroll
  for (int m = 0; m < 6; ++m)
#pragma unroll
    for (int j = 0; j < 2; ++j) acc[m][j] = (floatx4)(0.f);

  // phase 0: stage A[s=0..6], compute
  for (int i = threadIdx.x; i < APH / 8; i += 512)
    ((uint4*)Ls)[i] = ((const uint4*)wr)[i];
  __syncthreads();
  kphase<0>(xp0, xp1, Ls, n, quad, qhalf, acc);

  // phase 1: restage A[s=7..13], compute
  __syncthreads();
  for (int i = threadIdx.x; i < APH / 8; i += 512)
    ((uint4*)Ls)[i] = ((const uint4*)(wr + APH))[i];
  __syncthreads();
  kphase<1>(xp0, xp1, Ls, n, quad, qhalf, acc);

  // epilogue: bias + activation -> interleaved gates in LDS
  // slot (u16) = (c*8 + w)*SSTR + t*6 + g   (g == m, plane order preserved)
  __syncthreads();
#pragma unroll
  for (int m = 0; m < 6; ++m) {
    const bool isTanh = (m == 0) || (m == 5);
#pragma unroll
    for (int rr = 0; rr < 4; ++rr) {
      const int c = quad * 4 + rr;
      const float bias = cb[m * 16 + c];
#pragma unroll
      for (int j = 0; j < 2; ++j) {
        const int t = wv * 4 + j * 2 + th;
        float v = acc[m][j][rr] + bias;
        v = isTanh ? tanh_(v) : sigmoid_(v);
        Ls[(c * 8 + wloc) * SSTR + t * 6 + m] = f2h(v);
      }
    }
  }
  __syncthreads();

  // bidirectional scan: 128 threads, one (c, w) series each (T_=31 steps),
  // loads batched in chunks of 8 steps.
  if (threadIdx.x < 128) {
    const int ser = threadIdx.x;
    const int c = ser >> 3, w = ser & 7;
    const u16* gp = Ls + ser * SSTR;
    float htl[T_];
    float C = 0.f;
#pragma unroll
    for (int c8 = 0; c8 < 4; ++c8) {
      const int nt = (c8 == 3) ? 7 : 8;
      u32 a0[8], a1[8], a2[8];
#pragma unroll
      for (int i = 0; i < 8; ++i)
        if (i < nt) {
          const u16* tp = gp + (c8 * 8 + i) * 6;
          a0[i] = *(const u32*)tp;        // wx | f<<16
          a1[i] = *(const u32*)(tp + 2);  // f2 | r<<16
          a2[i] = *(const u32*)(tp + 4);  // r2 | x<<16
        }
#pragma unroll
      for (int i = 0; i < 8; ++i)
        if (i < nt) {
          const int t = c8 * 8 + i;
          const float wx = h2f((u16)(a0[i] & 0xffffu));
          const float f  = h2f((u16)(a0[i] >> 16));
          const float r  = h2f((u16)(a1[i] >> 16));
          const float xv = h2f((u16)(a2[i] >> 16));
          C = (t == 0) ? (1.f - f) : (f * C + (1.f - f) * wx);
          htl[t] = r * C + (1.f - r) * xv;
        }
    }
    const size_t ob =
        ((size_t)(b * COUT + c) * T_) * HW + h * W_ + wbase + w;
    float C2 = 0.f;
#pragma unroll
    for (int c8 = 3; c8 >= 0; --c8) {
      const int nt = (c8 == 3) ? 7 : 8;
      u32 a0[8], a1[8], a2[8];
#pragma unroll
      for (int i = 0; i < 8; ++i)
        if (i < nt) {
          const u16* tp = gp + (c8 * 8 + i) * 6;
          a0[i] = *(const u32*)tp;
          a1[i] = *(const u32*)(tp + 2);
          a2[i] = *(const u32*)(tp + 4);
        }
#pragma unroll
      for (int i = 7; i >= 0; --i)
        if (i < nt) {
          const int t = c8 * 8 + i;
          const float wx = h2f((u16)(a0[i] & 0xffffu));
          const float f2 = h2f((u16)(a1[i] & 0xffffu));
          const float r2 = h2f((u16)(a2[i] & 0xffffu));
          const float xv = h2f((u16)(a2[i] >> 16));
          C2 = (t == T_ - 1) ? (1.f - f2) : (f2 * C2 + (1.f - f2) * wx);
          const float htr = r2 * C2 + (1.f - r2) * xv;
          out[ob + (size_t)t * HW] = htl[t] + htr;
        }
    }
  }
}

// ---------------------------------------------------------------------------
// Fallback path (only if ws too small for the fused MFMA path).
// ---------------------------------------------------------------------------
__global__ __launch_bounds__(256) void sru_scan_kernel(
    const u16* __restrict__ g, float* __restrict__ out) {
  const int idx  = blockIdx.x * 256 + threadIdx.x;
  const int sp   = idx & (HW - 1);
  const int bc   = idx >> 14;
  const int base = bc * (T_ * HW) + sp;
  const int P    = B_ * COUT * T_ * HW;

  const u16* gWx = g + 0 * P + base;
  const u16* gF  = g + 1 * P + base;
  const u16* gF2 = g + 2 * P + base;
  const u16* gR  = g + 3 * P + base;
  const u16* gR2 = g + 4 * P + base;
  const u16* gX  = g + 5 * P + base;

  float wxs[T_], xs[T_], htl[T_];
  float C = 0.f;
#pragma unroll
  for (int t = 0; t < T_; ++t) {
    const float wx = h2f(gWx[t * HW]);
    const float f  = h2f(gF[t * HW]);
    const float r  = h2f(gR[t * HW]);
    const float xv = h2f(gX[t * HW]);
    wxs[t] = wx;
    xs[t]  = xv;
    C = (t == 0) ? (1.f - f) : (f * C + (1.f - f) * wx);
    htl[t] = r * C + (1.f - r) * xv;
  }
  float C2 = 0.f;
#pragma unroll
  for (int t = T_ - 1; t >= 0; --t) {
    const float f2 = h2f(gF2[t * HW]);
    const float r2 = h2f(gR2[t * HW]);
    C2 = (t == T_ - 1) ? (1.f - f2) : (f2 * C2 + (1.f - f2) * wxs[t]);
    const float htr = r2 * C2 + (1.f - r2) * xs[t];
    out[base + t * HW] = htl[t] + htr;
  }
}

__global__ __launch_bounds__(256) void conv_gates_kernel(
    const float* __restrict__ x, const float* __restrict__ cw,
    const float* __restrict__ cb, u16* __restrict__ gates) {
  const int sp = blockIdx.x * 256 + threadIdx.x;
  const int oc = blockIdx.y;
  const int bt = blockIdx.z;
  const int b  = bt / T_;
  const int t  = bt - b * T_;
  const int h  = sp >> 7;
  const int wc = sp & (W_ - 1);

  __shared__ float wsh[KVOL];
  for (int i = threadIdx.x; i < KVOL; i += 256) wsh[i] = cw[oc * KVOL + i];
  __syncthreads();

  float acc = cb[oc];
  const float* xb = x + b * (CIN * T_ * HW);
  for (int ci = 0; ci < CIN; ++ci) {
    const float* xc = xb + ci * (T_ * HW);
#pragma unroll
    for (int kd = 0; kd < 3; ++kd) {
      const int tt = t + kd - 1;
      if ((unsigned)tt >= (unsigned)T_) continue;
      const float* xt = xc + tt * HW;
#pragma unroll
      for (int kh = 0; kh < 3; ++kh) {
        const int hh = h + kh - 1;
        if ((unsigned)hh >= (unsigned)H_) continue;
        const float* xr = xt + hh * W_;
        const float* wrp = &wsh[(ci * 3 + kd) * 9 + kh * 3];
        if (wc > 0)      acc += wrp[0] * xr[wc - 1];
        acc += wrp[1] * xr[wc];
        if (wc < W_ - 1) acc += wrp[2] * xr[wc + 1];
      }
    }
  }
  const int g = oc >> 4, c = oc & 15;
  const float av = (g == 0 || g == 5) ? tanh_(acc) : sigmoid_(acc);
  const int off = (((g * B_ + b) * COUT + c) * T_ + t) * HW + sp;
  gates[off] = f2h(av);
}

extern "C" void kernel_launch(void* const* d_in, const int* in_sizes, int n_in,
                              void* d_out, int out_size, void* d_ws,
                              size_t ws_size, hipStream_t stream) {
  (void)in_sizes; (void)n_in; (void)out_size;
  const float* x  = (const float*)d_in[0];
  const float* cw = (const float*)d_in[1];
  const float* cb = (const float*)d_in[2];
  float* out = (float*)d_out;

  const size_t planeElems = (size_t)B_ * COUT * T_ * HW;    // 16,252,928
  const size_t szGatesH = 6 * planeElems * sizeof(u16);     // 195,035,136
  const size_t szX      = (size_t)NPADX * 16 * sizeof(u16); // 36,233,600
  const size_t szW      = (size_t)OC * KP * sizeof(u16);    // 86,016

  char* p = (char*)d_ws;
  if (ws_size >= szX + szW) {
    u16* xh  = (u16*)p;
    u16* wrp = (u16*)(p + szX);
    prep_kernel<<<PADBLK + WBLK, 256, 0, stream>>>(x, cw, xh, wrp);
    const dim3 gfused(W_ / 8, H_, B_);   // 16 x 128 x 2 = 4096 blocks
    conv_sru_fused<<<gfused, 512, 0, stream>>>(xh, wrp, cb, out);
  } else if (ws_size >= szGatesH) {
    u16* gates = (u16*)p;
    const dim3 gdir(HW / 256, OC, B_ * T_);
    conv_gates_kernel<<<gdir, 256, 0, stream>>>(x, cw, cb, gates);
    const int scanBlocks = (B_ * COUT * HW) / 256;
    sru_scan_kernel<<<scanBlocks, 256, 0, stream>>>(gates, out);
  }
}

// Round 9
// 245.114 us; speedup vs baseline: 1.0651x; 1.0449x over previous
//
#include <hip/hip_runtime.h>

#define DEVFN __device__ __forceinline__

typedef __attribute__((ext_vector_type(8))) short short8;
typedef __attribute__((ext_vector_type(4))) float floatx4;
typedef unsigned short u16;
typedef unsigned int u32;

constexpr int B_   = 2;
constexpr int CIN  = 16;
constexpr int COUT = 16;
constexpr int T_   = 31;
constexpr int H_   = 128;
constexpr int W_   = 128;
constexpr int OC   = 6 * COUT;   // 96
constexpr int HW   = H_ * W_;    // 16384
constexpr int KVOL = CIN * 27;   // 432
constexpr int KP   = 448;        // K padded to 14 * 32

// padded x layout [b][TP][HP][WP][16ci], fp16
constexpr int TP = T_ + 2;       // 33
constexpr int HP = H_ + 2;       // 130
constexpr int WP = W_ + 2;       // 130
constexpr int Sh = WP * 16;      // elems per hh step
constexpr int St = HP * Sh;      // elems per tt step
constexpr int NPAD  = B_ * TP * HP * WP;   // 1,115,400 positions
// +1 zeroed t-slab: fused kernel's pad column t=31 reads padded tt up to 33.
constexpr int NPADX = NPAD + HP * WP;      // 1,132,300
constexpr int PADBLK = (NPADX + 255) / 256;
constexpr int WBLK   = (OC * KP + 255) / 256;

// A-in-LDS: one phase = 7 k-steps, layout [sl(7)][m(6)][quad(4)][n(16)][j(8)]
constexpr int APH = 7 * 6 * 4 * 16 * 8;  // 21504 elems = 43008 B per phase

// gates-in-LDS (alias over A buffer after conv): [ser(128)][slot(38)][6 u16]
// ser = c*8+w; slot = t + 2*(ser>>5)  (per-series t-rotation).
// SSTR = 230 u16 = 115 words === 19 (mod 32), gcd(19,32)=1:
//  - epilogue packed-u32 writes: banks (rr*8+w)*19 + 6q + 3t -> <=2-way (free)
//  - scan reads: consecutive ser -> stride-19 bank walk, <=2 lanes/bank.
// One (c,w,t)'s 6 gates contiguous -> epilogue emits 3 x u32 (was 48 u16
// scalar stores, 4-way quad-collision = R8's 3.1M bank conflicts).
constexpr int SSTR = 230;                // u16 per series (38 slots x 6)
constexpr int GL2  = 128 * SSTR;         // 29440 u16 = 58880 B
constexpr int LSN  = (GL2 > APH) ? GL2 : APH;   // 29440 u16

DEVFN float sigmoid_(float v) { return 1.f / (1.f + __expf(-v)); }
DEVFN float tanh_(float v)    { return 1.f - 2.f / (__expf(2.f * v) + 1.f); }

DEVFN u16 f2h(float v) {  // RNE f32 -> fp16 raw bits
  _Float16 h = (_Float16)v;
  u16 u; __builtin_memcpy(&u, &h, 2); return u;
}
DEVFN float h2f(u16 u) {
  _Float16 h; __builtin_memcpy(&h, &u, 2); return (float)h;
}

// delta (in elems) into padded-x for kernel offset off = kd*9+kh*3+kw;
// off==27 (the K pad) clamps to 26 — A weights there are zero.
DEVFN constexpr int dOff(int off) {
  const int o = (off < 27) ? off : 26;
  return (o / 9) * St + ((o % 9) / 3) * Sh + (o % 3) * 16;
}

// ---------------------------------------------------------------------------
// Prep (merged): blocks [0, PADBLK) do x fp32->fp16 pad/transpose, ONE
// position per thread (4 B lane stride, fully coalesced); blocks
// [PADBLK, PADBLK+WBLK) reorder weights to the LDS-ready layout.
// ---------------------------------------------------------------------------
__global__ __launch_bounds__(256) void prep_kernel(const float* __restrict__ x,
                                                   const float* __restrict__ cw,
                                                   u16* __restrict__ xh,
                                                   u16* __restrict__ wr) {
  if (blockIdx.x < PADBLK) {
    const int idx = blockIdx.x * 256 + threadIdx.x;
    if (idx >= NPADX) return;
    int r = idx;
    const int ww = r % WP; r /= WP;
    const int hh = r % HP; r /= HP;
    const int tt = r % TP; const int b = r / TP;
    const bool in_ = (b < B_) & (tt >= 1) & (tt <= T_) & (hh >= 1) &
                     (hh <= H_) & (ww >= 1) & (ww <= W_);
    const int ts = in_ ? tt - 1 : 0, hs = in_ ? hh - 1 : 0,
              ws = in_ ? ww - 1 : 0;
    const int bs = (b < B_) ? b : 0;
    const float* xp = x + ((size_t)bs * CIN * T_ + ts) * HW + hs * W_ + ws;
    u32 ph[8];
#pragma unroll
    for (int ci = 0; ci < 16; ++ci) {
      const float v = in_ ? xp[ci * (T_ * HW)] : 0.f;
      const u16 hu = f2h(v);
      if (ci & 1) ph[ci >> 1] |= ((u32)hu) << 16;
      else        ph[ci >> 1] = hu;
    }
    uint4* dh = (uint4*)(xh + (size_t)idx * 16);
    dh[0] = make_uint4(ph[0], ph[1], ph[2], ph[3]);
    dh[1] = make_uint4(ph[4], ph[5], ph[6], ph[7]);
  } else {
    // weights [oc][ci][27] fp32 -> [s(14)][m(6)][quad(4)][n(16)][j(8)] fp16,
    // oc = m*16+n, k = s*32+quad*8+j.
    const int idx = (blockIdx.x - PADBLK) * 256 + threadIdx.x;
    if (idx >= OC * KP) return;
    const int j    = idx & 7;
    const int n    = (idx >> 3) & 15;
    const int quad = (idx >> 7) & 3;
    const int m    = (idx >> 9) % 6;
    const int s    = idx / 3072;
    const int oc   = m * 16 + n;
    const int kk   = s * 32 + quad * 8 + j;
    const int off  = kk >> 4, ci = kk & 15;
    const float v  = (off < 27) ? cw[oc * KVOL + ci * 27 + off] : 0.f;
    wr[idx] = f2h(v);
  }
}

// ---------------------------------------------------------------------------
// One k-phase (7 steps), PH compile-time so dOff folds to immediates.
// 2 B-loads + 12 MFMA per step (8-wave variant). Compiler-scheduled (R4's
// hand pipeline regressed 155->190 us — do not re-introduce explicit
// prefetch buffers here).
// ---------------------------------------------------------------------------
template <int PH>
DEVFN void kphase(const u16* __restrict__ xp0, const u16* __restrict__ xp1,
                  const u16* As, int n, int quad, int qhalf,
                  floatx4 (&acc)[6][2]) {
#pragma unroll
  for (int sl = 0; sl < 7; ++sl) {
    const int s = PH * 7 + sl;
    const int d = qhalf ? dOff(2 * s + 1) : dOff(2 * s);
    short8 bh[2];
    bh[0] = *(const short8*)(xp0 + d);
    bh[1] = *(const short8*)(xp1 + d);
#pragma unroll
    for (int m = 0; m < 6; ++m) {
      const short8 a =
          *(const short8*)(As + (sl * 6 + m) * 512 + quad * 128 + n * 8);
#pragma unroll
      for (int j = 0; j < 2; ++j)
        acc[m][j] =
            __builtin_amdgcn_mfma_f32_16x16x32_f16(a, bh[j], acc[m][j], 0, 0, 0);
    }
  }
}

// ---------------------------------------------------------------------------
// Fused conv + bidirectional SRU scan — 8-wave variant (R6 conv structure)
// + interleaved gates (R8) + conflict-free packed epilogue (this round).
// Block = 8 waves (512 thr) = one (b, h, 8w) tile covering ALL t:
//   wave wv owns t = wv*4 + j*2 + th (j=0..1, th=(lane>>3)&1) -> acc[6][2].
//   t==31 is a discarded pad col. MFMA fragment layouts HW-verified.
// Epilogue: per (c,w,t) compute all 6 activations, store as 3 u32 at
// slot (t + 2*quad) — 24 u32 stores/thread, <=2-way banks.
// Scan: threads 0..127, one (c,w) series each; 3 u32 loads per step,
// batched 8 steps ahead of the dependent chain (static indexing).
// ---------------------------------------------------------------------------
__global__ __launch_bounds__(512, 4) void conv_sru_fused(
    const u16* __restrict__ xh, const u16* __restrict__ wr,
    const float* __restrict__ cb, float* __restrict__ out) {
  const int lane = threadIdx.x & 63, wv = threadIdx.x >> 6;  // wv = 0..7
  const int n = lane & 15, quad = lane >> 4;
  const int qhalf = quad >> 1, cihalf = quad & 1;
  const int th = n >> 3, wloc = n & 7;
  const int wbase = blockIdx.x * 8;
  const int h = blockIdx.y;
  const int b = blockIdx.z;

  __shared__ __align__(16) u16 Ls[LSN];  // 58880 B (A phases alias gates)

  // per-thread base pointers for the 2 column tiles (j -> t += 2)
  const u16 *xp0, *xp1;
  {
    const int t0 = wv * 4 + th;
    const size_t pb =
        ((size_t)((b * TP + t0) * HP + h) * WP + wbase + wloc) * 16 +
        cihalf * 8;
    xp0 = xh + pb;
    xp1 = xh + pb + (size_t)2 * St;
  }

  floatx4 acc[6][2];
#pragma unroll
  for (int m = 0; m < 6; ++m)
#pragma unroll
    for (int j = 0; j < 2; ++j) acc[m][j] = (floatx4)(0.f);

  // phase 0: stage A[s=0..6], compute
  for (int i = threadIdx.x; i < APH / 8; i += 512)
    ((uint4*)Ls)[i] = ((const uint4*)wr)[i];
  __syncthreads();
  kphase<0>(xp0, xp1, Ls, n, quad, qhalf, acc);

  // phase 1: restage A[s=7..13], compute
  __syncthreads();
  for (int i = threadIdx.x; i < APH / 8; i += 512)
    ((uint4*)Ls)[i] = ((const uint4*)(wr + APH))[i];
  __syncthreads();
  kphase<1>(xp0, xp1, Ls, n, quad, qhalf, acc);

  // epilogue: bias + activation -> packed interleaved gates in LDS
  __syncthreads();
  {
    const int rot = 2 * quad;  // per-series t-rotation (ser>>5 == quad)
#pragma unroll
    for (int rr = 0; rr < 4; ++rr) {
      const int c = quad * 4 + rr;
      float bs[6];
#pragma unroll
      for (int m = 0; m < 6; ++m) bs[m] = cb[m * 16 + c];
      u16* sp = Ls + (c * 8 + wloc) * SSTR;
#pragma unroll
      for (int j = 0; j < 2; ++j) {
        const int t = wv * 4 + j * 2 + th;
        float v[6];
#pragma unroll
        for (int m = 0; m < 6; ++m) {
          const float a = acc[m][j][rr] + bs[m];
          v[m] = (m == 0 || m == 5) ? tanh_(a) : sigmoid_(a);
        }
        u32* wp = (u32*)(sp + (t + rot) * 6);
        wp[0] = (u32)f2h(v[0]) | ((u32)f2h(v[1]) << 16);  // wx | f
        wp[1] = (u32)f2h(v[2]) | ((u32)f2h(v[3]) << 16);  // f2 | r
        wp[2] = (u32)f2h(v[4]) | ((u32)f2h(v[5]) << 16);  // r2 | x
      }
    }
  }
  __syncthreads();

  // bidirectional scan: 128 threads, one (c, w) series each (T_=31 steps),
  // loads batched in chunks of 8 steps.
  if (threadIdx.x < 128) {
    const int ser = threadIdx.x;
    const int c = ser >> 3, w = ser & 7;
    const u16* gp = Ls + ser * SSTR + (ser >> 5) * 12;  // fold t-rotation
    float htl[T_];
    float C = 0.f;
#pragma unroll
    for (int c8 = 0; c8 < 4; ++c8) {
      const int nt = (c8 == 3) ? 7 : 8;
      u32 a0[8], a1[8], a2[8];
#pragma unroll
      for (int i = 0; i < 8; ++i)
        if (i < nt) {
          const u16* tp = gp + (c8 * 8 + i) * 6;
          a0[i] = *(const u32*)tp;        // wx | f<<16
          a1[i] = *(const u32*)(tp + 2);  // f2 | r<<16
          a2[i] = *(const u32*)(tp + 4);  // r2 | x<<16
        }
#pragma unroll
      for (int i = 0; i < 8; ++i)
        if (i < nt) {
          const int t = c8 * 8 + i;
          const float wx = h2f((u16)(a0[i] & 0xffffu));
          const float f  = h2f((u16)(a0[i] >> 16));
          const float r  = h2f((u16)(a1[i] >> 16));
          const float xv = h2f((u16)(a2[i] >> 16));
          C = (t == 0) ? (1.f - f) : (f * C + (1.f - f) * wx);
          htl[t] = r * C + (1.f - r) * xv;
        }
    }
    const size_t ob =
        ((size_t)(b * COUT + c) * T_) * HW + h * W_ + wbase + w;
    float C2 = 0.f;
#pragma unroll
    for (int c8 = 3; c8 >= 0; --c8) {
      const int nt = (c8 == 3) ? 7 : 8;
      u32 a0[8], a1[8], a2[8];
#pragma unroll
      for (int i = 0; i < 8; ++i)
        if (i < nt) {
          const u16* tp = gp + (c8 * 8 + i) * 6;
          a0[i] = *(const u32*)tp;
          a1[i] = *(const u32*)(tp + 2);
          a2[i] = *(const u32*)(tp + 4);
        }
#pragma unroll
      for (int i = 7; i >= 0; --i)
        if (i < nt) {
          const int t = c8 * 8 + i;
          const float wx = h2f((u16)(a0[i] & 0xffffu));
          const float f2 = h2f((u16)(a1[i] & 0xffffu));
          const float r2 = h2f((u16)(a2[i] & 0xffffu));
          const float xv = h2f((u16)(a2[i] >> 16));
          C2 = (t == T_ - 1) ? (1.f - f2) : (f2 * C2 + (1.f - f2) * wx);
          const float htr = r2 * C2 + (1.f - r2) * xv;
          out[ob + (size_t)t * HW] = htl[t] + htr;
        }
    }
  }
}

// ---------------------------------------------------------------------------
// Fallback path (only if ws too small for the fused MFMA path).
// ---------------------------------------------------------------------------
__global__ __launch_bounds__(256) void sru_scan_kernel(
    const u16* __restrict__ g, float* __restrict__ out) {
  const int idx  = blockIdx.x * 256 + threadIdx.x;
  const int sp   = idx & (HW - 1);
  const int bc   = idx >> 14;
  const int base = bc * (T_ * HW) + sp;
  const int P    = B_ * COUT * T_ * HW;

  const u16* gWx = g + 0 * P + base;
  const u16* gF  = g + 1 * P + base;
  const u16* gF2 = g + 2 * P + base;
  const u16* gR  = g + 3 * P + base;
  const u16* gR2 = g + 4 * P + base;
  const u16* gX  = g + 5 * P + base;

  float wxs[T_], xs[T_], htl[T_];
  float C = 0.f;
#pragma unroll
  for (int t = 0; t < T_; ++t) {
    const float wx = h2f(gWx[t * HW]);
    const float f  = h2f(gF[t * HW]);
    const float r  = h2f(gR[t * HW]);
    const float xv = h2f(gX[t * HW]);
    wxs[t] = wx;
    xs[t]  = xv;
    C = (t == 0) ? (1.f - f) : (f * C + (1.f - f) * wx);
    htl[t] = r * C + (1.f - r) * xv;
  }
  float C2 = 0.f;
#pragma unroll
  for (int t = T_ - 1; t >= 0; --t) {
    const float f2 = h2f(gF2[t * HW]);
    const float r2 = h2f(gR2[t * HW]);
    C2 = (t == T_ - 1) ? (1.f - f2) : (f2 * C2 + (1.f - f2) * wxs[t]);
    const float htr = r2 * C2 + (1.f - r2) * xs[t];
    out[base + t * HW] = htl[t] + htr;
  }
}

__global__ __launch_bounds__(256) void conv_gates_kernel(
    const float* __restrict__ x, const float* __restrict__ cw,
    const float* __restrict__ cb, u16* __restrict__ gates) {
  const int sp = blockIdx.x * 256 + threadIdx.x;
  const int oc = blockIdx.y;
  const int bt = blockIdx.z;
  const int b  = bt / T_;
  const int t  = bt - b * T_;
  const int h  = sp >> 7;
  const int wc = sp & (W_ - 1);

  __shared__ float wsh[KVOL];
  for (int i = threadIdx.x; i < KVOL; i += 256) wsh[i] = cw[oc * KVOL + i];
  __syncthreads();

  float acc = cb[oc];
  const float* xb = x + b * (CIN * T_ * HW);
  for (int ci = 0; ci < CIN; ++ci) {
    const float* xc = xb + ci * (T_ * HW);
#pragma unroll
    for (int kd = 0; kd < 3; ++kd) {
      const int tt = t + kd - 1;
      if ((unsigned)tt >= (unsigned)T_) continue;
      const float* xt = xc + tt * HW;
#pragma unroll
      for (int kh = 0; kh < 3; ++kh) {
        const int hh = h + kh - 1;
        if ((unsigned)hh >= (unsigned)H_) continue;
        const float* xr = xt + hh * W_;
        const float* wrp = &wsh[(ci * 3 + kd) * 9 + kh * 3];
        if (wc > 0)      acc += wrp[0] * xr[wc - 1];
        acc += wrp[1] * xr[wc];
        if (wc < W_ - 1) acc += wrp[2] * xr[wc + 1];
      }
    }
  }
  const int g = oc >> 4, c = oc & 15;
  const float av = (g == 0 || g == 5) ? tanh_(acc) : sigmoid_(acc);
  const int off = (((g * B_ + b) * COUT + c) * T_ + t) * HW + sp;
  gates[off] = f2h(av);
}

extern "C" void kernel_launch(void* const* d_in, const int* in_sizes, int n_in,
                              void* d_out, int out_size, void* d_ws,
                              size_t ws_size, hipStream_t stream) {
  (void)in_sizes; (void)n_in; (void)out_size;
  const float* x  = (const float*)d_in[0];
  const float* cw = (const float*)d_in[1];
  const float* cb = (const float*)d_in[2];
  float* out = (float*)d_out;

  const size_t planeElems = (size_t)B_ * COUT * T_ * HW;    // 16,252,928
  const size_t szGatesH = 6 * planeElems * sizeof(u16);     // 195,035,136
  const size_t szX      = (size_t)NPADX * 16 * sizeof(u16); // 36,233,600
  const size_t szW      = (size_t)OC * KP * sizeof(u16);    // 86,016

  char* p = (char*)d_ws;
  if (ws_size >= szX + szW) {
    u16* xh  = (u16*)p;
    u16* wrp = (u16*)(p + szX);
    prep_kernel<<<PADBLK + WBLK, 256, 0, stream>>>(x, cw, xh, wrp);
    const dim3 gfused(W_ / 8, H_, B_);   // 16 x 128 x 2 = 4096 blocks
    conv_sru_fused<<<gfused, 512, 0, stream>>>(xh, wrp, cb, out);
  } else if (ws_size >= szGatesH) {
    u16* gates = (u16*)p;
    const dim3 gdir(HW / 256, OC, B_ * T_);
    conv_gates_kernel<<<gdir, 256, 0, stream>>>(x, cw, cb, gates);
    const int scanBlocks = (B_ * COUT * HW) / 256;
    sru_scan_kernel<<<scanBlocks, 256, 0, stream>>>(gates, out);
  }
}